// Round 1
// baseline (1923.854 us; speedup 1.0000x reference)
//
#include <hip/hip_runtime.h>

#define T_LEN 2048
#define BATCH 512
#define HID   25
#define NNOTES 51
#define EMBED 50
#define G4    100   // 4*HID

__device__ __forceinline__ float bcastf(float v, int lane) {
  return __int_as_float(__builtin_amdgcn_readlane(__float_as_int(v), lane));
}
__device__ __forceinline__ float sigf(float x) {
  return __builtin_amdgcn_rcpf(1.0f + __expf(-x));
}
__device__ __forceinline__ float tanhfast(float x) {
  // tanh(x) = 1 - 2/(e^{2x}+1); correct limits at +-inf
  return 1.0f - 2.0f * __builtin_amdgcn_rcpf(1.0f + __expf(2.0f * x));
}

// Kernel 1: proj[n][j] = bih0[j] + bhh0[j] + sum_e Wih0[j,e]*emb[n,e]
__global__ void build_proj(const float* __restrict__ emb,
                           const float* __restrict__ Wih0,
                           const float* __restrict__ bih0,
                           const float* __restrict__ bhh0,
                           float* __restrict__ proj) {
  const int n = blockIdx.x;
  const int j = threadIdx.x;
  if (j < G4) {
    float acc = bih0[j] + bhh0[j];
    #pragma unroll
    for (int e = 0; e < EMBED; ++e)
      acc = fmaf(Wih0[j * EMBED + e], emb[n * EMBED + e], acc);
    proj[n * G4 + j] = acc;
  }
}

// Kernel 2: one wave per batch element. Lane l<50 owns gate rows l and l+50.
__global__ __launch_bounds__(64, 1) void lstm_seq(
    const int* __restrict__ x, const float* __restrict__ proj,
    const float* __restrict__ Whh0,
    const float* __restrict__ Wih1, const float* __restrict__ Whh1,
    const float* __restrict__ bih1, const float* __restrict__ bhh1,
    const float* __restrict__ fcW, const float* __restrict__ fcb,
    float* __restrict__ out) {
  __shared__ float projL[NNOTES * G4];
  __shared__ int   xL[T_LEN];

  const int l = threadIdx.x;
  const int b = blockIdx.x;

  for (int i = l; i < NNOTES * G4; i += 64) projL[i] = proj[i];
  const int* xrow = x + b * T_LEN;
  for (int i = l; i < T_LEN; i += 64) xL[i] = xrow[i];
  __syncthreads();

  const bool act = (l < 50);
  const int jA = l;
  const int jB = act ? (l + 50) : l;

  float w0A[HID], w0B[HID], wi1A[HID], wi1B[HID], wh1A[HID], wh1B[HID], fcw[HID];
  #pragma unroll
  for (int i = 0; i < HID; ++i) {
    w0A[i]  = act ? Whh0[jA * HID + i] : 0.0f;
    w0B[i]  = act ? Whh0[jB * HID + i] : 0.0f;
    wi1A[i] = act ? Wih1[jA * HID + i] : 0.0f;
    wi1B[i] = act ? Wih1[jB * HID + i] : 0.0f;
    wh1A[i] = act ? Whh1[jA * HID + i] : 0.0f;
    wh1B[i] = act ? Whh1[jB * HID + i] : 0.0f;
    fcw[i]  = (l < NNOTES) ? fcW[l * HID + i] : 0.0f;
  }
  const float b1A = act ? (bih1[jA] + bhh1[jA]) : 0.0f;
  const float b1B = act ? (bih1[jB] + bhh1[jB]) : 0.0f;
  const float fb  = (l < NNOTES) ? fcb[l] : 0.0f;

  float h0 = 0.f, c0 = 0.f, h1 = 0.f, c1 = 0.f;
  float* outrow = out + (size_t)b * T_LEN * NNOTES;

  // software-pipelined LDS prefetch of next step's xz lookup
  int note0 = xL[0];
  float zA = projL[note0 * G4 + jA];
  float zB = projL[note0 * G4 + jB];

  for (int t = 0; t < T_LEN; ++t) {
    float zAc = zA, zBc = zB;
    {
      const int noteN = xL[(t + 1) & (T_LEN - 1)];
      zA = projL[noteN * G4 + jA];
      zB = projL[noteN * G4 + jB];
    }
    // ---- layer 0: z = xz + Whh0 @ h0 ----
    #pragma unroll
    for (int i = 0; i < HID; ++i) {
      const float h = bcastf(h0, i);
      zAc = fmaf(w0A[i], h, zAc);
      zBc = fmaf(w0B[i], h, zBc);
    }
    {
      const float zi = zAc, zg = zBc;                 // i-gate (k), g-gate (k)
      const float zf = __shfl(zAc, l + 25, 64);       // f-gate (k+25)
      const float zo = __shfl(zBc, l + 25, 64);       // o-gate (k+75)
      const float cn = sigf(zf) * c0 + sigf(zi) * tanhfast(zg);
      c0 = cn;
      h0 = sigf(zo) * tanhfast(cn);
    }
    // ---- layer 1: z = bih1+bhh1 + Wih1 @ h0 + Whh1 @ h1 ----
    float yA = b1A, yB = b1B;
    #pragma unroll
    for (int i = 0; i < HID; ++i) {
      const float ha = bcastf(h0, i);
      const float hb = bcastf(h1, i);
      yA = fmaf(wi1A[i], ha, yA);
      yA = fmaf(wh1A[i], hb, yA);
      yB = fmaf(wi1B[i], ha, yB);
      yB = fmaf(wh1B[i], hb, yB);
    }
    {
      const float zi = yA, zg = yB;
      const float zf = __shfl(yA, l + 25, 64);
      const float zo = __shfl(yB, l + 25, 64);
      const float cn = sigf(zf) * c1 + sigf(zi) * tanhfast(zg);
      c1 = cn;
      h1 = sigf(zo) * tanhfast(cn);
    }
    // ---- FC head: logits = fcW @ h1 + fcb ----
    float acc = fb;
    #pragma unroll
    for (int i = 0; i < HID; ++i)
      acc = fmaf(fcw[i], bcastf(h1, i), acc);
    if (l < NNOTES) outrow[t * NNOTES + l] = acc;
  }

  // final states: h_n [2,B,H] then c_n [2,B,H]
  if (l < HID) {
    const size_t baseH = (size_t)BATCH * T_LEN * NNOTES;   // 53477376
    const size_t baseC = baseH + (size_t)2 * BATCH * HID;  // +25600
    out[baseH + (size_t)b * HID + l]                      = h0;
    out[baseH + (size_t)BATCH * HID + (size_t)b * HID + l] = h1;
    out[baseC + (size_t)b * HID + l]                      = c0;
    out[baseC + (size_t)BATCH * HID + (size_t)b * HID + l] = c1;
  }
}

extern "C" void kernel_launch(void* const* d_in, const int* in_sizes, int n_in,
                              void* d_out, int out_size, void* d_ws, size_t ws_size,
                              hipStream_t stream) {
  const int*   x    = (const int*)d_in[0];
  const float* emb  = (const float*)d_in[1];
  const float* Wih0 = (const float*)d_in[2];
  const float* Whh0 = (const float*)d_in[3];
  const float* bih0 = (const float*)d_in[4];
  const float* bhh0 = (const float*)d_in[5];
  const float* Wih1 = (const float*)d_in[6];
  const float* Whh1 = (const float*)d_in[7];
  const float* bih1 = (const float*)d_in[8];
  const float* bhh1 = (const float*)d_in[9];
  const float* fcW  = (const float*)d_in[10];
  const float* fcb  = (const float*)d_in[11];
  float* out  = (float*)d_out;
  float* proj = (float*)d_ws;  // 51*100 floats = 20.4 KB

  build_proj<<<NNOTES, 128, 0, stream>>>(emb, Wih0, bih0, bhh0, proj);
  lstm_seq<<<BATCH, 64, 0, stream>>>(x, proj, Whh0, Wih1, Whh1, bih1, bhh1,
                                     fcW, fcb, out);
}

// Round 2
// 1467.982 us; speedup vs baseline: 1.3105x; 1.3105x over previous
//
#include <hip/hip_runtime.h>

#define T_LEN 2048
#define BATCH 512
#define HID   25
#define NNOTES 51
#define EMBED 50
#define G4    100   // 4*HID

typedef float v2f __attribute__((ext_vector_type(2)));

#define REP25(M) M(0) M(1) M(2) M(3) M(4) M(5) M(6) M(7) M(8) M(9) \
  M(10) M(11) M(12) M(13) M(14) M(15) M(16) M(17) M(18) M(19) \
  M(20) M(21) M(22) M(23) M(24)

#define NL2E 1.442695041f   // log2(e)

#if __has_builtin(__builtin_amdgcn_exp2f)
#define EXP2(x) __builtin_amdgcn_exp2f(x)
#else
#define EXP2(x) __expf((x) * 0.6931471805599453f)
#endif

__device__ __forceinline__ float bcastf(float v, int lane) {
  return __int_as_float(__builtin_amdgcn_readlane(__float_as_int(v), lane));
}
__device__ __forceinline__ float rcpf_(float x) { return __builtin_amdgcn_rcpf(x); }
__device__ __forceinline__ v2f mk2(float a, float b) { v2f r; r.x = a; r.y = b; return r; }

// zA carries sigmoid-rows (i or f); zB carries (g or o): lanes<25 need tanh on zB,
// lanes 25-49 need sigmoid. sB/aB/bB are per-lane constants selecting the variant.
__device__ __forceinline__ void gates(float zA, float zB, float& c, float& h,
                                      float sB, float aB, float bB, int paddr) {
  float uA = rcpf_(1.0f + EXP2(zA * (-NL2E)));          // sigmoid(zA)
  float eB = EXP2(zB * sB);
  float uB = rcpf_(1.0f + eB);
  float rB = fmaf(aB, uB, bB);                          // tanh(zB) or sigmoid(zB)
  float sf = __int_as_float(__builtin_amdgcn_ds_bpermute(paddr, __float_as_int(uA)));
  float so = __int_as_float(__builtin_amdgcn_ds_bpermute(paddr, __float_as_int(rB)));
  float cn = fmaf(sf, c, uA * rB);
  c = cn;
  float th = fmaf(2.0f, rcpf_(1.0f + EXP2(cn * (-2.0f * NL2E))), -1.0f);
  h = so * th;
}

// Kernel 1: proj[n][j] = bih0[j] + bhh0[j] + sum_e Wih0[j,e]*emb[n,e]
__global__ void build_proj(const float* __restrict__ emb,
                           const float* __restrict__ Wih0,
                           const float* __restrict__ bih0,
                           const float* __restrict__ bhh0,
                           float* __restrict__ proj) {
  const int n = blockIdx.x;
  const int j = threadIdx.x;
  if (j < G4) {
    float acc = bih0[j] + bhh0[j];
    #pragma unroll
    for (int e = 0; e < EMBED; ++e)
      acc = fmaf(Wih0[j * EMBED + e], emb[n * EMBED + e], acc);
    proj[n * G4 + j] = acc;
  }
}

// Kernel 2: one wave per batch element. Lane l<50 owns gate rows l and l+50
// packed as a float2 (v_pk_fma_f32 path).
__global__ __launch_bounds__(64, 1) __attribute__((amdgpu_waves_per_eu(1, 1)))
void lstm_seq(
    const int* __restrict__ x, const float* __restrict__ proj,
    const float* __restrict__ Whh0,
    const float* __restrict__ Wih1, const float* __restrict__ Whh1,
    const float* __restrict__ bih1, const float* __restrict__ bhh1,
    const float* __restrict__ fcW, const float* __restrict__ fcb,
    float* __restrict__ out) {
  __shared__ float projL[NNOTES * G4];
  __shared__ int   xL[T_LEN];

  const int l = threadIdx.x;
  const int b = blockIdx.x;

  for (int i = l; i < NNOTES * G4; i += 64) projL[i] = proj[i];
  const int* xrow = x + b * T_LEN;
  for (int i = l; i < T_LEN; i += 64) xL[i] = xrow[i];
  __syncthreads();

  const bool act = (l < 50);
  const bool lo  = (l < 25);
  const int jA = act ? l : 0;
  const int jB = act ? (l + 50) : 0;
  const int paddr = ((l + 25) & 63) << 2;

  const float sB = lo ? (-2.0f * NL2E) : (-NL2E);
  const float aB = lo ? 2.0f : 1.0f;
  const float bB = lo ? -1.0f : 0.0f;

  // Weights: constant-index init (bulletproof SROA -> VGPRs)
  v2f w0[HID], wi1[HID], wh1[HID];
  float fcw[HID];
#define LDW(i) \
  w0[i]  = act ? mk2(Whh0[jA*HID+(i)], Whh0[jB*HID+(i)]) : mk2(0.f,0.f); \
  wi1[i] = act ? mk2(Wih1[jA*HID+(i)], Wih1[jB*HID+(i)]) : mk2(0.f,0.f); \
  wh1[i] = act ? mk2(Whh1[jA*HID+(i)], Whh1[jB*HID+(i)]) : mk2(0.f,0.f); \
  fcw[i] = (l < NNOTES) ? fcW[l*HID+(i)] : 0.0f;
  REP25(LDW)
#undef LDW
  const v2f b1 = act ? mk2(bih1[jA] + bhh1[jA], bih1[jB] + bhh1[jB]) : mk2(0.f, 0.f);
  const float fb = (l < NNOTES) ? fcb[l] : 0.0f;

  float h0 = 0.f, c0 = 0.f, h1 = 0.f, c1 = 0.f;
  float h0b[HID], h1b[HID];
#define Z25(i) h0b[i] = 0.0f; h1b[i] = 0.0f;
  REP25(Z25)
#undef Z25

  float* outrow = out + (size_t)b * T_LEN * NNOTES;

  // software-pipelined prefetch of next step's xz pair
  int n0 = xL[0];
  v2f xz = mk2(projL[n0 * G4 + jA], projL[n0 * G4 + jB]);

  for (int t = 0; t < T_LEN; ++t) {
    const v2f xzc = xz;
    {
      const int nn = xL[(t + 1) & (T_LEN - 1)];
      xz = mk2(projL[nn * G4 + jA], projL[nn * G4 + jB]);
    }

    // ---- layer 0: z = xz + Whh0 @ h0 (packed rows, 2 chains) ----
    v2f zp0 = xzc, zp1 = mk2(0.f, 0.f);
#define L0S(i) { const v2f hh = { h0b[i], h0b[i] }; \
    if ((i) & 1) zp1 = __builtin_elementwise_fma(w0[i], hh, zp1); \
    else         zp0 = __builtin_elementwise_fma(w0[i], hh, zp0); }
    REP25(L0S)
#undef L0S
    const v2f z0 = zp0 + zp1;
    gates(z0.x, z0.y, c0, h0, sB, aB, bB, paddr);
#define BC0(i) h0b[i] = bcastf(h0, i);
    REP25(BC0)
#undef BC0

    // ---- layer 1: z = b1 + Wih1 @ h0 + Whh1 @ h1 (packed, 4 chains) ----
    v2f y0 = b1, y1 = mk2(0.f, 0.f), y2 = mk2(0.f, 0.f), y3 = mk2(0.f, 0.f);
#define L1S(i) { const v2f ha = { h0b[i], h0b[i] }; const v2f hb = { h1b[i], h1b[i] }; \
    if ((i) & 1) { y1 = __builtin_elementwise_fma(wi1[i], ha, y1); \
                   y3 = __builtin_elementwise_fma(wh1[i], hb, y3); } \
    else         { y0 = __builtin_elementwise_fma(wi1[i], ha, y0); \
                   y2 = __builtin_elementwise_fma(wh1[i], hb, y2); } }
    REP25(L1S)
#undef L1S
    const v2f z1v = (y0 + y1) + (y2 + y3);
    gates(z1v.x, z1v.y, c1, h1, sB, aB, bB, paddr);
#define BC1(i) h1b[i] = bcastf(h1, i);
    REP25(BC1)
#undef BC1

    // ---- FC head: logits = fcW @ h1 + fcb (2 chains) ----
    float a0 = fb, a1 = 0.f;
#define FCS(i) { if ((i) & 1) a1 = fmaf(fcw[i], h1b[i], a1); \
                 else         a0 = fmaf(fcw[i], h1b[i], a0); }
    REP25(FCS)
#undef FCS
    if (l < NNOTES) outrow[t * NNOTES + l] = a0 + a1;
  }

  // final states: h_n [2,B,H] then c_n [2,B,H]
  if (l < HID) {
    const size_t baseH = (size_t)BATCH * T_LEN * NNOTES;
    const size_t baseC = baseH + (size_t)2 * BATCH * HID;
    out[baseH + (size_t)b * HID + l]                       = h0;
    out[baseH + (size_t)BATCH * HID + (size_t)b * HID + l] = h1;
    out[baseC + (size_t)b * HID + l]                       = c0;
    out[baseC + (size_t)BATCH * HID + (size_t)b * HID + l] = c1;
  }
}

extern "C" void kernel_launch(void* const* d_in, const int* in_sizes, int n_in,
                              void* d_out, int out_size, void* d_ws, size_t ws_size,
                              hipStream_t stream) {
  const int*   x    = (const int*)d_in[0];
  const float* emb  = (const float*)d_in[1];
  const float* Wih0 = (const float*)d_in[2];
  const float* Whh0 = (const float*)d_in[3];
  const float* bih0 = (const float*)d_in[4];
  const float* bhh0 = (const float*)d_in[5];
  const float* Wih1 = (const float*)d_in[6];
  const float* Whh1 = (const float*)d_in[7];
  const float* bih1 = (const float*)d_in[8];
  const float* bhh1 = (const float*)d_in[9];
  const float* fcW  = (const float*)d_in[10];
  const float* fcb  = (const float*)d_in[11];
  float* out  = (float*)d_out;
  float* proj = (float*)d_ws;  // 51*100 floats = 20.4 KB

  build_proj<<<NNOTES, 128, 0, stream>>>(emb, Wih0, bih0, bhh0, proj);
  lstm_seq<<<BATCH, 64, 0, stream>>>(x, proj, Whh0, Wih1, Whh1, bih1, bhh1,
                                     fcW, fcb, out);
}